// Round 1
// baseline (858.532 us; speedup 1.0000x reference)
//
#include <hip/hip_runtime.h>
#include <math.h>

// Problem constants (from reference setup_inputs)
constexpr int Bq = 32;
constexpr int Tq = 8192;
constexpr int Dq = 8;
constexpr int Qq = 8;
constexpr int Kq = 1024;
constexpr int NTOK = Bq * Tq;                         // 262144 tokens
constexpr float LOSS_SCALE = 0.25f / (float)(Bq * Tq * Dq);

// One thread per token. Codebook for the current quantizer staged in LDS
// (32 KB) + its per-entry squared norms (4 KB). All lanes scan k in lockstep
// -> broadcast LDS reads (no bank conflicts).
//
// Numerics deliberately mimic the numpy reference op-for-op so the argmin
// matches at near-ties:
//   d2 = (rnorm + cnorm[k]) - 2*dot, dot = sequential FMA over d=0..7,
//   strict '<' keeps the FIRST minimum (np.argmin semantics).
__global__ __launch_bounds__(256, 4)
void rvq_main(const float* __restrict__ x,
              const float* __restrict__ codebooks,
              const float* __restrict__ post_scale,
              const float* __restrict__ post_bias,
              const float* __restrict__ conv_w,
              const float* __restrict__ conv_b,
              float* __restrict__ out)
{
    __shared__ __align__(16) float s_cb[Kq * Dq];   // 32 KB codebook tile
    __shared__ float s_cn[Kq];                      // 4 KB codeword norms

    const int tid = threadIdx.x;
    const int token = blockIdx.x * 256 + tid;       // grid covers exactly NTOK

    // residual r = x[token]
    float r[Dq];
    {
        const float4* xp = reinterpret_cast<const float4*>(x + (size_t)token * Dq);
        float4 a = xp[0], b = xp[1];
        r[0]=a.x; r[1]=a.y; r[2]=a.z; r[3]=a.w;
        r[4]=b.x; r[5]=b.y; r[6]=b.z; r[7]=b.w;
    }

    float qsum[Dq];
#pragma unroll
    for (int d = 0; d < Dq; ++d) qsum[d] = 0.0f;
    float lossacc = 0.0f;

    float* out_quant = out;                               // [B*T*D]
    float* out_loss  = out + (size_t)NTOK * Dq;           // [1]
    float* out_codes = out_loss + 1;                      // [Q*B*T] as float

    for (int q = 0; q < Qq; ++q) {
        // ---- stage codebook q into LDS (coalesced float4) ----
        {
            const float4* src = reinterpret_cast<const float4*>(
                codebooks + (size_t)q * Kq * Dq);
            float4* dst = reinterpret_cast<float4*>(s_cb);
#pragma unroll
            for (int i = 0; i < (Kq * Dq / 4) / 256; ++i)  // 8 iters
                dst[tid + i * 256] = src[tid + i * 256];
        }
        __syncthreads();

        // ---- per-codeword squared norms (np order: mul then sequential adds) ----
#pragma unroll
        for (int i = 0; i < Kq / 256; ++i) {               // 4 iters
            int k = tid + i * 256;
            const float* c = s_cb + k * Dq;
            float n = __fmul_rn(c[0], c[0]);
#pragma unroll
            for (int d = 1; d < Dq; ++d)
                n = __fadd_rn(n, __fmul_rn(c[d], c[d]));
            s_cn[k] = n;
        }
        __syncthreads();

        // ---- residual norm ----
        float rn = __fmul_rn(r[0], r[0]);
#pragma unroll
        for (int d = 1; d < Dq; ++d)
            rn = __fadd_rn(rn, __fmul_rn(r[d], r[d]));

        // ---- argmin over K codewords ----
        float best = __builtin_inff();
        int bk = 0;
        const float4* cb4 = reinterpret_cast<const float4*>(s_cb);
#pragma unroll 4
        for (int k = 0; k < Kq; ++k) {
            float4 c0 = cb4[2 * k];
            float4 c1 = cb4[2 * k + 1];
            float dot = __fmul_rn(r[0], c0.x);
            dot = fmaf(r[1], c0.y, dot);
            dot = fmaf(r[2], c0.z, dot);
            dot = fmaf(r[3], c0.w, dot);
            dot = fmaf(r[4], c1.x, dot);
            dot = fmaf(r[5], c1.y, dot);
            dot = fmaf(r[6], c1.z, dot);
            dot = fmaf(r[7], c1.w, dot);
            // (rn + cn[k]) - 2*dot ; 2*dot = dot+dot is exact
            float d2 = __fsub_rn(__fadd_rn(rn, s_cn[k]), __fadd_rn(dot, dot));
            if (d2 < best) { best = d2; bk = k; }          // first-min wins ties
        }

        // ---- gather chosen embed ----
        float e[Dq];
        {
            const float* c = s_cb + bk * Dq;
#pragma unroll
            for (int d = 0; d < Dq; ++d) e[d] = c[d];
        }

        out_codes[(size_t)q * NTOK + token] = (float)bk;

        const float sc = post_scale[q];
        const float bi = post_bias[q];
#pragma unroll
        for (int d = 0; d < Dq; ++d) {
            // STE forward value: r + (e - r)  (mimic rounding)
            float est = __fadd_rn(r[d], __fsub_rn(e[d], r[d]));
            // qsum = (qsum + est*s) + b
            qsum[d] = __fadd_rn(__fadd_rn(qsum[d], __fmul_rn(est, sc)), bi);
            // new_res = r - e ; loss term (new_res - e)^2
            float nr = __fsub_rn(r[d], e[d]);
            float df = __fsub_rn(nr, e[d]);
            lossacc = fmaf(df, df, lossacc);
            r[d] = nr;
        }
        __syncthreads();   // before next q overwrites s_cb
    }

    // ---- 1x1 conv epilogue: out[e] = dot(qsum, conv_w[e,:]) + conv_b[e] ----
    float o[Dq];
#pragma unroll
    for (int e = 0; e < Dq; ++e) {
        float acc = __fmul_rn(qsum[0], conv_w[e * Dq + 0]);
#pragma unroll
        for (int d = 1; d < Dq; ++d)
            acc = fmaf(qsum[d], conv_w[e * Dq + d], acc);
        o[e] = __fadd_rn(acc, conv_b[e]);
    }
    {
        float4* op = reinterpret_cast<float4*>(out_quant + (size_t)token * Dq);
        op[0] = make_float4(o[0], o[1], o[2], o[3]);
        op[1] = make_float4(o[4], o[5], o[6], o[7]);
    }

    // ---- loss reduction: wave butterfly, one atomic per wave ----
    float v = lossacc;
#pragma unroll
    for (int off = 32; off >= 1; off >>= 1)
        v += __shfl_xor(v, off, 64);
    if ((tid & 63) == 0)
        atomicAdd(out_loss, v * LOSS_SCALE);
}

extern "C" void kernel_launch(void* const* d_in, const int* in_sizes, int n_in,
                              void* d_out, int out_size, void* d_ws, size_t ws_size,
                              hipStream_t stream) {
    const float* x     = (const float*)d_in[0];
    const float* cb    = (const float*)d_in[1];
    const float* ps    = (const float*)d_in[2];
    const float* pb    = (const float*)d_in[3];
    const float* cw    = (const float*)d_in[4];
    const float* cbias = (const float*)d_in[5];
    float* out = (float*)d_out;

    // zero the loss accumulator slot (d_out is poisoned before every call)
    hipMemsetAsync(out + (size_t)NTOK * Dq, 0, sizeof(float), stream);

    rvq_main<<<dim3(NTOK / 256), dim3(256), 0, stream>>>(
        x, cb, ps, pb, cw, cbias, out);
}

// Round 2
// 813.116 us; speedup vs baseline: 1.0559x; 1.0559x over previous
//
#include <hip/hip_runtime.h>
#include <math.h>

// Problem constants (from reference setup_inputs)
constexpr int Bq = 32;
constexpr int Tq = 8192;
constexpr int Dq = 8;
constexpr int Qq = 8;
constexpr int Kq = 1024;
constexpr int NTOK = Bq * Tq;                         // 262144 tokens
constexpr float LOSS_SCALE = 0.25f / (float)(Bq * Tq * Dq);

// Round 2: TWO tokens per thread. Rationale: round-1 was LDS-return-path
// bound (2x ds_read_b128 + 1x ds_read_b32 = 36 B/lane/k ~= 288 cy/CU/k-step,
// measured 268). Reading the codeword once per thread and reusing it for two
// tokens halves LDS bytes per (token,k) pair. d2 numerics stay op-for-op
// identical to the passing round-1 kernel:
//   d2 = (rn + cn[k]) - 2*dot  computed as  fmaf(dot, -2.0f, rn + cn[k])
// (bit-identical: 2*dot is exact, so the fused form rounds s-2dot once,
//  same as __fsub_rn(s, __fadd_rn(dot,dot))). Strict '<' keeps first min.
__global__ __launch_bounds__(256, 2)
void rvq_main(const float* __restrict__ x,
              const float* __restrict__ codebooks,
              const float* __restrict__ post_scale,
              const float* __restrict__ post_bias,
              const float* __restrict__ conv_w,
              const float* __restrict__ conv_b,
              float* __restrict__ out)
{
    __shared__ __align__(16) float s_cb[Kq * Dq];   // 32 KB codebook tile
    __shared__ float s_cn[Kq];                      // 4 KB codeword norms

    const int tid = threadIdx.x;
    const int tok0 = blockIdx.x * 512 + tid;        // grid 512 covers 2*256*512
    const int tok1 = tok0 + 256;

    // residuals
    float r0[Dq], r1[Dq];
    {
        const float4* xp0 = reinterpret_cast<const float4*>(x + (size_t)tok0 * Dq);
        float4 a = xp0[0], b = xp0[1];
        r0[0]=a.x; r0[1]=a.y; r0[2]=a.z; r0[3]=a.w;
        r0[4]=b.x; r0[5]=b.y; r0[6]=b.z; r0[7]=b.w;
        const float4* xp1 = reinterpret_cast<const float4*>(x + (size_t)tok1 * Dq);
        float4 c = xp1[0], d = xp1[1];
        r1[0]=c.x; r1[1]=c.y; r1[2]=c.z; r1[3]=c.w;
        r1[4]=d.x; r1[5]=d.y; r1[6]=d.z; r1[7]=d.w;
    }

    float qs0[Dq], qs1[Dq];
#pragma unroll
    for (int d = 0; d < Dq; ++d) { qs0[d] = 0.0f; qs1[d] = 0.0f; }
    float lossacc = 0.0f;

    float* out_quant = out;                               // [B*T*D]
    float* out_loss  = out + (size_t)NTOK * Dq;           // [1]
    float* out_codes = out_loss + 1;                      // [Q*B*T] as float

    for (int q = 0; q < Qq; ++q) {
        // ---- stage codebook q into LDS (coalesced float4) ----
        {
            const float4* src = reinterpret_cast<const float4*>(
                codebooks + (size_t)q * Kq * Dq);
            float4* dst = reinterpret_cast<float4*>(s_cb);
#pragma unroll
            for (int i = 0; i < (Kq * Dq / 4) / 256; ++i)  // 8 iters
                dst[tid + i * 256] = src[tid + i * 256];
        }
        __syncthreads();

        // ---- per-codeword squared norms (np order) ----
#pragma unroll
        for (int i = 0; i < Kq / 256; ++i) {               // 4 iters
            int k = tid + i * 256;
            const float* c = s_cb + k * Dq;
            float n = __fmul_rn(c[0], c[0]);
#pragma unroll
            for (int d = 1; d < Dq; ++d)
                n = __fadd_rn(n, __fmul_rn(c[d], c[d]));
            s_cn[k] = n;
        }
        __syncthreads();

        // ---- residual norms ----
        float rn0 = __fmul_rn(r0[0], r0[0]);
        float rn1 = __fmul_rn(r1[0], r1[0]);
#pragma unroll
        for (int d = 1; d < Dq; ++d) {
            rn0 = __fadd_rn(rn0, __fmul_rn(r0[d], r0[d]));
            rn1 = __fadd_rn(rn1, __fmul_rn(r1[d], r1[d]));
        }

        // ---- argmin over K codewords, two tokens sharing each LDS read ----
        float best0 = __builtin_inff(), best1 = __builtin_inff();
        int bk0 = 0, bk1 = 0;
        const float4* cb4 = reinterpret_cast<const float4*>(s_cb);
#pragma unroll 2
        for (int k = 0; k < Kq; ++k) {
            float4 c0 = cb4[2 * k];
            float4 c1 = cb4[2 * k + 1];
            float cn = s_cn[k];

            float dot0 = __fmul_rn(r0[0], c0.x);
            dot0 = fmaf(r0[1], c0.y, dot0);
            dot0 = fmaf(r0[2], c0.z, dot0);
            dot0 = fmaf(r0[3], c0.w, dot0);
            dot0 = fmaf(r0[4], c1.x, dot0);
            dot0 = fmaf(r0[5], c1.y, dot0);
            dot0 = fmaf(r0[6], c1.z, dot0);
            dot0 = fmaf(r0[7], c1.w, dot0);
            float d20 = fmaf(dot0, -2.0f, __fadd_rn(rn0, cn));
            if (d20 < best0) { best0 = d20; bk0 = k; }

            float dot1 = __fmul_rn(r1[0], c0.x);
            dot1 = fmaf(r1[1], c0.y, dot1);
            dot1 = fmaf(r1[2], c0.z, dot1);
            dot1 = fmaf(r1[3], c0.w, dot1);
            dot1 = fmaf(r1[4], c1.x, dot1);
            dot1 = fmaf(r1[5], c1.y, dot1);
            dot1 = fmaf(r1[6], c1.z, dot1);
            dot1 = fmaf(r1[7], c1.w, dot1);
            float d21 = fmaf(dot1, -2.0f, __fadd_rn(rn1, cn));
            if (d21 < best1) { best1 = d21; bk1 = k; }
        }

        // ---- gather chosen embeds, update state ----
        const float sc = post_scale[q];
        const float bi = post_bias[q];

        out_codes[(size_t)q * NTOK + tok0] = (float)bk0;
        out_codes[(size_t)q * NTOK + tok1] = (float)bk1;

        {
            const float* c = s_cb + bk0 * Dq;
#pragma unroll
            for (int d = 0; d < Dq; ++d) {
                float e = c[d];
                float est = __fadd_rn(r0[d], __fsub_rn(e, r0[d]));
                qs0[d] = __fadd_rn(__fadd_rn(qs0[d], __fmul_rn(est, sc)), bi);
                float nr = __fsub_rn(r0[d], e);
                float df = __fsub_rn(nr, e);
                lossacc = fmaf(df, df, lossacc);
                r0[d] = nr;
            }
        }
        {
            const float* c = s_cb + bk1 * Dq;
#pragma unroll
            for (int d = 0; d < Dq; ++d) {
                float e = c[d];
                float est = __fadd_rn(r1[d], __fsub_rn(e, r1[d]));
                qs1[d] = __fadd_rn(__fadd_rn(qs1[d], __fmul_rn(est, sc)), bi);
                float nr = __fsub_rn(r1[d], e);
                float df = __fsub_rn(nr, e);
                lossacc = fmaf(df, df, lossacc);
                r1[d] = nr;
            }
        }
        __syncthreads();   // before next q overwrites s_cb
    }

    // ---- 1x1 conv epilogue ----
    {
        float o[Dq];
#pragma unroll
        for (int e = 0; e < Dq; ++e) {
            float acc = __fmul_rn(qs0[0], conv_w[e * Dq + 0]);
#pragma unroll
            for (int d = 1; d < Dq; ++d)
                acc = fmaf(qs0[d], conv_w[e * Dq + d], acc);
            o[e] = __fadd_rn(acc, conv_b[e]);
        }
        float4* op = reinterpret_cast<float4*>(out_quant + (size_t)tok0 * Dq);
        op[0] = make_float4(o[0], o[1], o[2], o[3]);
        op[1] = make_float4(o[4], o[5], o[6], o[7]);
    }
    {
        float o[Dq];
#pragma unroll
        for (int e = 0; e < Dq; ++e) {
            float acc = __fmul_rn(qs1[0], conv_w[e * Dq + 0]);
#pragma unroll
            for (int d = 1; d < Dq; ++d)
                acc = fmaf(qs1[d], conv_w[e * Dq + d], acc);
            o[e] = __fadd_rn(acc, conv_b[e]);
        }
        float4* op = reinterpret_cast<float4*>(out_quant + (size_t)tok1 * Dq);
        op[0] = make_float4(o[0], o[1], o[2], o[3]);
        op[1] = make_float4(o[4], o[5], o[6], o[7]);
    }

    // ---- loss reduction: wave butterfly, one atomic per wave ----
    float v = lossacc;
#pragma unroll
    for (int off = 32; off >= 1; off >>= 1)
        v += __shfl_xor(v, off, 64);
    if ((tid & 63) == 0)
        atomicAdd(out_loss, v * LOSS_SCALE);
}

extern "C" void kernel_launch(void* const* d_in, const int* in_sizes, int n_in,
                              void* d_out, int out_size, void* d_ws, size_t ws_size,
                              hipStream_t stream) {
    const float* x     = (const float*)d_in[0];
    const float* cb    = (const float*)d_in[1];
    const float* ps    = (const float*)d_in[2];
    const float* pb    = (const float*)d_in[3];
    const float* cw    = (const float*)d_in[4];
    const float* cbias = (const float*)d_in[5];
    float* out = (float*)d_out;

    // zero the loss accumulator slot (d_out is poisoned before every call)
    hipMemsetAsync(out + (size_t)NTOK * Dq, 0, sizeof(float), stream);

    rvq_main<<<dim3(NTOK / 512), dim3(256), 0, stream>>>(
        x, cb, ps, pb, cw, cbias, out);
}